// Round 1
// baseline (304.278 us; speedup 1.0000x reference)
//
#include <hip/hip_runtime.h>

#define WIRE_DIM  32
#define NUM_WIRES 64
#define BATCH     8192
#define HID       10
#define NB        4          // batches per wave

__global__ __launch_bounds__(256) void isnet_kernel(
    const float* __restrict__ outputs,
    const int*   __restrict__ tests,
    const float* __restrict__ W1,
    const float* __restrict__ b1,
    const float* __restrict__ W2,
    const float* __restrict__ b2,
    float*       __restrict__ out)
{
    // W1 transposed in LDS: sW1t[h*64 + d] = W1[d*10 + h], so per-h reads are
    // contiguous float4 (ds_read_b128, wave-uniform addr -> broadcast, 0 conflicts)
    __shared__ __align__(16) float sW1t[HID * 64];
    __shared__ float sB1[HID], sW2[HID], sB2;

    const int tid  = threadIdx.x;
    const int lane = tid & 63;
    const int wave = tid >> 6;

    for (int i = tid; i < 64 * HID; i += 256) {
        int d = i / HID;
        int h = i - d * HID;
        sW1t[h * 64 + d] = W1[i];
    }
    if (tid < HID) { sB1[tid] = b1[tid]; sW2[tid] = W2[tid]; }
    if (tid == 0)  sB2 = b2[0];
    __syncthreads();

    const int b0 = blockIdx.x * (4 * NB) + wave * NB;

    const float* rowp[NB];   // person vector (wave-uniform address per batch)
    const float* roww[NB];   // this lane's wire row
    int loc[NB];
    #pragma unroll
    for (int nb = 0; nb < NB; ++nb) {
        int bb = b0 + nb;
        int person = tests[2 * bb];
        loc[nb]    = tests[2 * bb + 1];
        const float* row = outputs + (size_t)bb * (NUM_WIRES * WIRE_DIM);
        rowp[nb] = row + person * WIRE_DIM;
        roww[nb] = row + lane * WIRE_DIM;
    }

    float acc[NB][HID];
    #pragma unroll
    for (int nb = 0; nb < NB; ++nb)
        #pragma unroll
        for (int h = 0; h < HID; ++h) acc[nb][h] = sB1[h];

    // first half of x: person vector -> W1 rows 0..31 (W1t columns 0..31)
    #pragma unroll
    for (int j = 0; j < 8; ++j) {
        float4 x[NB];
        #pragma unroll
        for (int nb = 0; nb < NB; ++nb) x[nb] = *(const float4*)(rowp[nb] + 4 * j);
        #pragma unroll
        for (int h = 0; h < HID; ++h) {
            float4 w = *(const float4*)&sW1t[h * 64 + 4 * j];
            #pragma unroll
            for (int nb = 0; nb < NB; ++nb)
                acc[nb][h] += x[nb].x * w.x + x[nb].y * w.y
                            + x[nb].z * w.z + x[nb].w * w.w;
        }
    }
    // second half of x: own wire -> W1 rows 32..63 (W1t columns 32..63)
    #pragma unroll
    for (int j = 0; j < 8; ++j) {
        float4 x[NB];
        #pragma unroll
        for (int nb = 0; nb < NB; ++nb) x[nb] = *(const float4*)(roww[nb] + 4 * j);
        #pragma unroll
        for (int h = 0; h < HID; ++h) {
            float4 w = *(const float4*)&sW1t[h * 64 + 32 + 4 * j];
            #pragma unroll
            for (int nb = 0; nb < NB; ++nb)
                acc[nb][h] += x[nb].x * w.x + x[nb].y * w.y
                            + x[nb].z * w.z + x[nb].w * w.w;
        }
    }

    // epilogue per batch: relu -> W2 -> logit (one per lane=wire) -> wave softmax
    #pragma unroll
    for (int nb = 0; nb < NB; ++nb) {
        float v = sB2;
        #pragma unroll
        for (int h = 0; h < HID; ++h) v += fmaxf(acc[nb][h], 0.f) * sW2[h];

        float m = v;
        #pragma unroll
        for (int off = 32; off > 0; off >>= 1) m = fmaxf(m, __shfl_xor(m, off));
        float e = __expf(v - m);
        float s = e;
        #pragma unroll
        for (int off = 32; off > 0; off >>= 1) s += __shfl_xor(s, off);
        float lv = __shfl(v, loc[nb]);           // logit at `location` wire
        if (lane == nb) out[b0 + nb] = m + __logf(s) - lv;   // -log_softmax[loc]
    }
}

extern "C" void kernel_launch(void* const* d_in, const int* in_sizes, int n_in,
                              void* d_out, int out_size, void* d_ws, size_t ws_size,
                              hipStream_t stream) {
    const float* outputs = (const float*)d_in[0];
    const int*   tests   = (const int*)d_in[1];
    const float* W1      = (const float*)d_in[2];
    const float* b1      = (const float*)d_in[3];
    const float* W2      = (const float*)d_in[4];
    const float* b2      = (const float*)d_in[5];
    float* out = (float*)d_out;

    // 16 batches per block (4 waves x NB=4) -> 512 blocks
    isnet_kernel<<<BATCH / (4 * NB), 256, 0, stream>>>(
        outputs, tests, W1, b1, W2, b2, out);
}